// Round 12
// baseline (145.444 us; speedup 1.0000x reference)
//
#include <hip/hip_runtime.h>
#include <math.h>

#define NN 384
#define NSQ (NN*NN)          // 147456

// workspace float offsets
#define WS_MASKF 0           // 384
#define WS_C1    384         // 384*8   = 3072
#define WS_P     3456        // 384*512 = 196608
#define WS_VN    200064      // 384*256 = 98304
#define WS_GH    494976      // 64*384  = 24576
#define WS_WT    519552      // 64*64 bf16 (2048 floats used)  WtBF[o][c] = We[o,256+c]
#define WS_WOT   523648      // 256*128 = 32768  Wo^T            [dd][o]
#define WS_WVE   556416      // 64*256  = 16384  Wv[:,128:192]^T [c][d]
#define WS_WEN   572800      // 256*64  = 16384  We[:,0:256]^T   [dd][o]
#define WS_TP    602112      // T halves: [i][jh][512] f32 = 393216 floats
#define WS_MS    995328      // m: [i][jh][8] (6144) then sum: +6144

typedef short short8 __attribute__((ext_vector_type(8)));
typedef float f32x4 __attribute__((ext_vector_type(4)));

__device__ __forceinline__ unsigned short f2bf(float x) {
    unsigned u = __float_as_uint(x);
    return (unsigned short)((u + 0x7FFFu + ((u >> 16) & 1u)) >> 16);
}
__device__ __forceinline__ float bf2f(unsigned short b) {
    return __uint_as_float(((unsigned)b) << 16);
}

// ---------------------------------------------------------------------------
// K1: projections + c1 + P. (R11 version verbatim: 96 main blocks x 4 cols,
// float4 weight rows.) Aux blocks 96..100: mask / WtBF / WoT / WvE / WeN.
__global__ __launch_bounds__(256) void k_proj(
    const float* __restrict__ nodes, const float* __restrict__ Wq,
    const float* __restrict__ Wk, const float* __restrict__ Wv,
    const float* __restrict__ Wo, const float* __restrict__ We,
    const unsigned int* __restrict__ mi, float* __restrict__ ws) {
    int tid = threadIdx.x;
    if (blockIdx.x >= 96) {
        if (blockIdx.x == 96) {
            __shared__ int bytemode;
            if (tid == 0) bytemode = 0;
            __syncthreads();
            unsigned v0 = mi[tid];
            unsigned v1 = (tid < 128) ? mi[256 + tid] : 0u;
            if (v0 > 1u || v1 > 1u) bytemode = 1;   // benign race
            __syncthreads();
            float* maskf = ws + WS_MASKF;
            for (int j = tid; j < NN; j += 256) {
                int on;
                if (bytemode) on = (((const unsigned char*)mi)[j] != 0);
                else          on = (mi[j] != 0u);
                maskf[j] = on ? 1.0f : 0.0f;
            }
        } else if (blockIdx.x == 97) {
            unsigned short* WtBF = reinterpret_cast<unsigned short*>(ws + WS_WT);
            for (int idx = tid; idx < 4096; idx += 256) {
                int o = idx >> 6, c = idx & 63;
                WtBF[o * 64 + c] = f2bf(We[o * 320 + 256 + c]);
            }
        } else if (blockIdx.x == 98) {
            float* WoT = ws + WS_WOT;
            for (int idx = tid; idx < 32768; idx += 256) {
                int dd = idx >> 7, o = idx & 127;
                WoT[dd * 128 + o] = Wo[o * 256 + dd];
            }
        } else if (blockIdx.x == 99) {
            float* WvE = ws + WS_WVE;
            for (int idx = tid; idx < 16384; idx += 256) {
                int c = idx >> 8, d = idx & 255;
                WvE[c * 256 + d] = Wv[d * 192 + 128 + c];
            }
        } else {
            float* WeN = ws + WS_WEN;
            for (int idx = tid; idx < 16384; idx += 256) {
                int dd = idx >> 6, o = idx & 63;
                WeN[dd * 64 + o] = We[o * 320 + dd];
            }
        }
        return;
    }
    float* c1_ws = ws + WS_C1;
    float* P_ws  = ws + WS_P;
    float* vn_ws = ws + WS_VN;
    int i0 = blockIdx.x * 4;
    __shared__ float nl[128][4];
    __shared__ float q_l[256][4];
    __shared__ float qk_l[256][4];
    for (int idx = tid; idx < 512; idx += 256) {
        int m = idx >> 2, ii = idx & 3;
        nl[m][ii] = nodes[m * NN + i0 + ii];
    }
    __syncthreads();
    int o = tid;
    float aq[4], ak[4], av[4];
#pragma unroll
    for (int ii = 0; ii < 4; ii++) { aq[ii] = 0.f; ak[ii] = 0.f; av[ii] = 0.f; }
    {
        const float4* wq4 = reinterpret_cast<const float4*>(Wq + o * 128);
        const float4* wk4 = reinterpret_cast<const float4*>(Wk + o * 192);
        const float4* wv4 = reinterpret_cast<const float4*>(Wv + o * 192);
#pragma unroll 8
        for (int m4 = 0; m4 < 32; m4++) {
            float4 wq = wq4[m4];
            float4 wk = wk4[m4];
            float4 wv = wv4[m4];
#pragma unroll
            for (int s = 0; s < 4; s++) {
                int m = m4 * 4 + s;
                float fq = s == 0 ? wq.x : s == 1 ? wq.y : s == 2 ? wq.z : wq.w;
                float fk = s == 0 ? wk.x : s == 1 ? wk.y : s == 2 ? wk.z : wk.w;
                float fv = s == 0 ? wv.x : s == 1 ? wv.y : s == 2 ? wv.z : wv.w;
#pragma unroll
                for (int ii = 0; ii < 4; ii++) {
                    float nv = nl[m][ii];
                    aq[ii] = fmaf(fq, nv, aq[ii]);
                    ak[ii] = fmaf(fk, nv, ak[ii]);
                    av[ii] = fmaf(fv, nv, av[ii]);
                }
            }
        }
    }
#pragma unroll
    for (int ii = 0; ii < 4; ii++) {
        vn_ws[(size_t)(i0 + ii) * 256 + o] = av[ii];
        q_l[o][ii]  = aq[ii];
        qk_l[o][ii] = aq[ii] * ak[ii];
    }
    __syncthreads();
    if (tid < 32) {
        int h = tid >> 2, ii = tid & 3;
        float s = 0.f;
        for (int a = 0; a < 32; a++) s += qk_l[h * 32 + a][ii];
        c1_ws[(i0 + ii) * 8 + h] = s;
    }
    for (int rep = 0; rep < 2; rep++) {
        int idx = rep * 256 + tid;
        int c = idx & 63, h = idx >> 6;
        float ap[4];
#pragma unroll
        for (int ii = 0; ii < 4; ii++) ap[ii] = 0.f;
        for (int a = 0; a < 32; a++) {
            float w = Wk[(h * 32 + a) * 192 + 128 + c];
#pragma unroll
            for (int ii = 0; ii < 4; ii++)
                ap[ii] = fmaf(q_l[h * 32 + a][ii], w, ap[ii]);
        }
#pragma unroll
        for (int ii = 0; ii < 4; ii++)
            P_ws[(size_t)(i0 + ii) * 512 + c * 8 + h] = ap[ii];
    }
}

// ---------------------------------------------------------------------------
// K2 (FLASH half-row attn): grid (384 i, 2 jh) = 768 blocks = exactly 3/CU
// (was 384 = 1.5/CU -> half the CUs ran 2 sequential full-row chains).
// Each block: stage e-half bf16 (all 512 thr, coalesced), sim-half, LOCAL
// softmax p=exp(sim-m_half) (unnormalized), partial PV via MFMA (6 K-steps),
// write (m,sum,T_half) to ws. k_comb merges halves + runs tails.
__global__ __launch_bounds__(512) void k_attn(
    const float* __restrict__ edges, float* __restrict__ ws) {
    __shared__ __align__(16) unsigned short epad_h[64 * 200];  // 25600 B
    __shared__ __align__(16) float sT2[192 * 8];               // 6144 B
    const float* maskf = ws + WS_MASKF;
    const float* c1w   = ws + WS_C1;
    const float* Pw    = ws + WS_P;
    int i = blockIdx.x, jh = blockIdx.y;
    int tid = threadIdx.x;
    int wv = tid >> 6, ln = tid & 63;

    // stage: thread (c = tid>>3, g = tid&7) loads e[c, i, jh*192+g*24 ..+23]
    {
        int c = tid >> 3, g = tid & 7;
        const float* src = edges + (size_t)c * NSQ + (size_t)i * NN + jh * 192 + g * 24;
        float4 v0 = reinterpret_cast<const float4*>(src)[0];
        float4 v1 = reinterpret_cast<const float4*>(src)[1];
        float4 v2 = reinterpret_cast<const float4*>(src)[2];
        float4 v3 = reinterpret_cast<const float4*>(src)[3];
        float4 v4 = reinterpret_cast<const float4*>(src)[4];
        float4 v5 = reinterpret_cast<const float4*>(src)[5];
        unsigned short* dst = &epad_h[c * 200 + g * 24];
#define PACK2(A, B, OFS)                                                     \
        {                                                                    \
            short8 p;                                                        \
            p[0] = (short)f2bf(A.x); p[1] = (short)f2bf(A.y);                \
            p[2] = (short)f2bf(A.z); p[3] = (short)f2bf(A.w);                \
            p[4] = (short)f2bf(B.x); p[5] = (short)f2bf(B.y);                \
            p[6] = (short)f2bf(B.z); p[7] = (short)f2bf(B.w);                \
            *reinterpret_cast<short8*>(dst + (OFS)) = p;                     \
        }
        PACK2(v0, v1, 0)
        PACK2(v2, v3, 8)
        PACK2(v4, v5, 16)
#undef PACK2
    }
    __syncthreads();

    // sim: thread j_loc (0..191) accumulates over c from LDS
    if (tid < 192) {
        int j_loc = tid, j = jh * 192 + j_loc;
        const float* Pi = Pw + (size_t)i * 512;
        float acc[8];
#pragma unroll
        for (int h = 0; h < 8; h++) acc[h] = 0.f;
#pragma unroll 8
        for (int c = 0; c < 64; c++) {
            float ev = bf2f(epad_h[c * 200 + j_loc]);
            const float* Pc = Pi + c * 8;     // wave-uniform -> s_load
#pragma unroll
            for (int h = 0; h < 8; h++) acc[h] = fmaf(Pc[h], ev, acc[h]);
        }
        float mj = maskf[j];
        const float* c1i = c1w + i * 8;
        float sv[8];
#pragma unroll
        for (int h = 0; h < 8; h++) {
            float s = (c1i[h] + acc[h]) * 0.17677669529663687f;
            sv[h] = (mj != 0.0f) ? s : -1e30f;
        }
        *reinterpret_cast<float4*>(&sT2[j_loc * 8])     = make_float4(sv[0], sv[1], sv[2], sv[3]);
        *reinterpret_cast<float4*>(&sT2[j_loc * 8 + 4]) = make_float4(sv[4], sv[5], sv[6], sv[7]);
    }
    __syncthreads();
    // local softmax: wave wv owns head h=wv; lanes cover j_loc = ln + 64k
    float v[3];
    {
        int h = wv;
#pragma unroll
        for (int k = 0; k < 3; k++) v[k] = sT2[(ln + 64 * k) * 8 + h];
    }
    __syncthreads();   // sT2 reads done; safe to overlay s_bf below
    {
        int h = wv;
        float m = fmaxf(fmaxf(v[0], v[1]), v[2]);
#pragma unroll
        for (int s = 1; s < 64; s <<= 1) m = fmaxf(m, __shfl_xor(m, s));
        float ex[3]; float sum = 0.f;
#pragma unroll
        for (int k = 0; k < 3; k++) { ex[k] = __expf(v[k] - m); sum += ex[k]; }
#pragma unroll
        for (int s = 1; s < 64; s <<= 1) sum += __shfl_xor(sum, s);
        unsigned short* s_bf = reinterpret_cast<unsigned short*>(sT2);
#pragma unroll
        for (int k = 0; k < 3; k++)
            s_bf[h * 200 + ln + 64 * k] = f2bf(ex[k]);   // unnormalized p <= 1
        if (ln == 0) {
            ws[WS_MS + (i * 2 + jh) * 8 + h] = m;
            ws[WS_MS + 6144 + (i * 2 + jh) * 8 + h] = sum;
        }
    }
    __syncthreads();
    // partial PV: 4 waves; wave wv owns c-tile wv; 6 K-steps (192 j).
    if (tid < 256) {
        const unsigned short* s_bf = reinterpret_cast<const unsigned short*>(sT2);
        int nc   = ln & 15;
        int quad = ln >> 4;
        int hrow = nc & 7;
        f32x4 acc = {0.f, 0.f, 0.f, 0.f};
#pragma unroll
        for (int s = 0; s < 6; s++) {
            int jb = s * 32 + quad * 8;
            short8 a = *reinterpret_cast<const short8*>(&s_bf[hrow * 200 + jb]);
            short8 b = *reinterpret_cast<const short8*>(&epad_h[(wv * 16 + nc) * 200 + jb]);
            acc = __builtin_amdgcn_mfma_f32_16x16x32_bf16(a, b, acc, 0, 0, 0);
        }
        if (ln < 32) {   // quads 0,1 -> D rows 0..7 (valid h)
            float* Tp = ws + WS_TP + (size_t)(i * 2 + jh) * 512;
#pragma unroll
            for (int r = 0; r < 4; r++) {
                int h = quad * 4 + r;
                Tp[h * 64 + wv * 16 + nc] = acc[r];
            }
        }
    }
}

// ---------------------------------------------------------------------------
// K3 (combine + tails): grid 384, 256 thr. Merge the two half-row partials:
// m=max(m1,m2); w=exp(mk-m); denom=w1*s1+w2*s2 (>=1 by construction);
// T = (w1*T1 + w2*T2) * mask_i/denom. Then the nf/out/gh tails (moved from
// the old fused k_attn -- same math, same fp32 order downstream of T).
__global__ __launch_bounds__(256) void k_comb(
    const float* __restrict__ ws_ro, float* __restrict__ gh_ws,
    float* __restrict__ out) {
    __shared__ __align__(16) float T_l[512];
    __shared__ float nf_l[256];
    __shared__ float a1s[8], a2s[8];
    const float* maskf = ws_ro + WS_MASKF;
    const float* vn_ws = ws_ro + WS_VN;
    const float* WvE   = ws_ro + WS_WVE;
    const float* WoT   = ws_ro + WS_WOT;
    const float* WeN   = ws_ro + WS_WEN;
    int i = blockIdx.x, tid = threadIdx.x;
    float mask_i = maskf[i];
    if (tid < 8) {
        int h = tid;
        float m1 = ws_ro[WS_MS + (i * 2 + 0) * 8 + h];
        float m2 = ws_ro[WS_MS + (i * 2 + 1) * 8 + h];
        float s1 = ws_ro[WS_MS + 6144 + (i * 2 + 0) * 8 + h];
        float s2 = ws_ro[WS_MS + 6144 + (i * 2 + 1) * 8 + h];
        float m = fmaxf(m1, m2);
        float w1 = __expf(m1 - m), w2 = __expf(m2 - m);
        float fac = mask_i / (w1 * s1 + w2 * s2);
        a1s[h] = w1 * fac;
        a2s[h] = w2 * fac;
    }
    __syncthreads();
    {
        const float* T1 = ws_ro + WS_TP + (size_t)(i * 2 + 0) * 512;
        const float* T2 = ws_ro + WS_TP + (size_t)(i * 2 + 1) * 512;
#pragma unroll
        for (int r = 0; r < 2; r++) {
            int t = tid + r * 256;
            int h = t >> 6;
            T_l[t] = a1s[h] * T1[t] + a2s[h] * T2[t];
        }
    }
    __syncthreads();
    // tail #1: nf[d] = mask_i*vn[i,d] + WvE^T @ T
    {
        int d = tid, h = d >> 5;
        float a0 = 0.f, a1 = 0.f, a2 = 0.f, a3 = 0.f;
#pragma unroll
        for (int c = 0; c < 64; c += 4) {
            a0 = fmaf(WvE[(c    ) * 256 + d], T_l[h * 64 + c    ], a0);
            a1 = fmaf(WvE[(c + 1) * 256 + d], T_l[h * 64 + c + 1], a1);
            a2 = fmaf(WvE[(c + 2) * 256 + d], T_l[h * 64 + c + 2], a2);
            a3 = fmaf(WvE[(c + 3) * 256 + d], T_l[h * 64 + c + 3], a3);
        }
        nf_l[d] = mask_i * vn_ws[(size_t)i * 256 + d] + ((a0 + a1) + (a2 + a3));
    }
    __syncthreads();
    // tail #2: node_out = Wo@nf ; gh = 0.5 * WeN@nf
    if (tid < 128) {
        int o = tid;
        float b0 = 0.f, b1 = 0.f, b2 = 0.f, b3 = 0.f;
#pragma unroll 8
        for (int dd = 0; dd < 256; dd += 4) {
            b0 = fmaf(WoT[(dd    ) * 128 + o], nf_l[dd    ], b0);
            b1 = fmaf(WoT[(dd + 1) * 128 + o], nf_l[dd + 1], b1);
            b2 = fmaf(WoT[(dd + 2) * 128 + o], nf_l[dd + 2], b2);
            b3 = fmaf(WoT[(dd + 3) * 128 + o], nf_l[dd + 3], b3);
        }
        out[o * NN + i] = (b0 + b1) + (b2 + b3);
    } else if (tid < 192) {
        int o = tid - 128;
        float b0 = 0.f, b1 = 0.f, b2 = 0.f, b3 = 0.f;
#pragma unroll 8
        for (int dd = 0; dd < 256; dd += 4) {
            b0 = fmaf(WeN[(dd    ) * 64 + o], nf_l[dd    ], b0);
            b1 = fmaf(WeN[(dd + 1) * 64 + o], nf_l[dd + 1], b1);
            b2 = fmaf(WeN[(dd + 2) * 64 + o], nf_l[dd + 2], b2);
            b3 = fmaf(WeN[(dd + 3) * 64 + o], nf_l[dd + 3], b3);
        }
        gh_ws[o * NN + i] = 0.5f * ((b0 + b1) + (b2 + b3));
    }
}

// ---------------------------------------------------------------------------
// K4: out_e[o,i,j] = gh[o,i]+gh[o,j]+sum_c WtBF[o][c]*e[c,i,j]   via MFMA.
// (R11 version verbatim: jh=8 split, 48 j's/block, 3072 blocks.)
__global__ __launch_bounds__(192) void k_edge(
    const float* __restrict__ edges, const float* __restrict__ ws_ro,
    float* __restrict__ out_e) {
    __shared__ __align__(16) unsigned short eT[48 * 72];  // [j_loc][c], 6912 B
    const unsigned short* WtBF = reinterpret_cast<const unsigned short*>(ws_ro + WS_WT);
    const float* gh = ws_ro + WS_GH;
    int i = blockIdx.x, jh = blockIdx.y, tid = threadIdx.x;

    {
        int ch = tid / 48, jl = tid - ch * 48;
        int c0 = ch * 16;
        const float* eb = edges + (size_t)c0 * NSQ + (size_t)i * NN + jh * 48 + jl;
        float ev[16];
#pragma unroll
        for (int t = 0; t < 16; t++)
            ev[t] = eb[(size_t)t * NSQ];
        short8 p0, p1;
#pragma unroll
        for (int t = 0; t < 8; t++) p0[t] = (short)f2bf(ev[t]);
#pragma unroll
        for (int t = 0; t < 8; t++) p1[t] = (short)f2bf(ev[t + 8]);
        *reinterpret_cast<short8*>(&eT[jl * 72 + c0])     = p0;
        *reinterpret_cast<short8*>(&eT[jl * 72 + c0 + 8]) = p1;
    }
    __syncthreads();

    int L = tid & 63, wv = tid >> 6;
    int nc = L & 15, quad = L >> 4;
    short8 a00 = *reinterpret_cast<const short8*>(&WtBF[(0 * 16 + nc) * 64 + 0  + quad * 8]);
    short8 a01 = *reinterpret_cast<const short8*>(&WtBF[(0 * 16 + nc) * 64 + 32 + quad * 8]);
    short8 a10 = *reinterpret_cast<const short8*>(&WtBF[(1 * 16 + nc) * 64 + 0  + quad * 8]);
    short8 a11 = *reinterpret_cast<const short8*>(&WtBF[(1 * 16 + nc) * 64 + 32 + quad * 8]);
    short8 a20 = *reinterpret_cast<const short8*>(&WtBF[(2 * 16 + nc) * 64 + 0  + quad * 8]);
    short8 a21 = *reinterpret_cast<const short8*>(&WtBF[(2 * 16 + nc) * 64 + 32 + quad * 8]);
    short8 a30 = *reinterpret_cast<const short8*>(&WtBF[(3 * 16 + nc) * 64 + 0  + quad * 8]);
    short8 a31 = *reinterpret_cast<const short8*>(&WtBF[(3 * 16 + nc) * 64 + 32 + quad * 8]);
    float ghi[16];
#pragma unroll
    for (int ot = 0; ot < 4; ot++)
#pragma unroll
        for (int r = 0; r < 4; r++)
            ghi[ot * 4 + r] = gh[(ot * 16 + quad * 4 + r) * NN + i];

    {
        int jt = wv;
        short8 b0 = *reinterpret_cast<const short8*>(&eT[(jt * 16 + nc) * 72 + 0  + quad * 8]);
        short8 b1 = *reinterpret_cast<const short8*>(&eT[(jt * 16 + nc) * 72 + 32 + quad * 8]);
        int j = jh * 48 + jt * 16 + nc;
        f32x4 c0 = {0.f, 0.f, 0.f, 0.f};
        f32x4 c1 = {0.f, 0.f, 0.f, 0.f};
        f32x4 c2 = {0.f, 0.f, 0.f, 0.f};
        f32x4 c3 = {0.f, 0.f, 0.f, 0.f};
        c0 = __builtin_amdgcn_mfma_f32_16x16x32_bf16(a00, b0, c0, 0, 0, 0);
        c0 = __builtin_amdgcn_mfma_f32_16x16x32_bf16(a01, b1, c0, 0, 0, 0);
        c1 = __builtin_amdgcn_mfma_f32_16x16x32_bf16(a10, b0, c1, 0, 0, 0);
        c1 = __builtin_amdgcn_mfma_f32_16x16x32_bf16(a11, b1, c1, 0, 0, 0);
        c2 = __builtin_amdgcn_mfma_f32_16x16x32_bf16(a20, b0, c2, 0, 0, 0);
        c2 = __builtin_amdgcn_mfma_f32_16x16x32_bf16(a21, b1, c2, 0, 0, 0);
        c3 = __builtin_amdgcn_mfma_f32_16x16x32_bf16(a30, b0, c3, 0, 0, 0);
        c3 = __builtin_amdgcn_mfma_f32_16x16x32_bf16(a31, b1, c3, 0, 0, 0);
#pragma unroll
        for (int ot = 0; ot < 4; ot++) {
            f32x4 cc = ot == 0 ? c0 : ot == 1 ? c1 : ot == 2 ? c2 : c3;
#pragma unroll
            for (int r = 0; r < 4; r++) {
                int o = ot * 16 + quad * 4 + r;
                float val = cc[r] + ghi[ot * 4 + r] + gh[o * NN + j];
                __builtin_nontemporal_store(val, &out_e[(size_t)o * NSQ + (size_t)i * NN + j]);
            }
        }
    }
}

// ---------------------------------------------------------------------------
extern "C" void kernel_launch(void* const* d_in, const int* in_sizes, int n_in,
                              void* d_out, int out_size, void* d_ws, size_t ws_size,
                              hipStream_t stream) {
    const float* nodes = (const float*)d_in[0];
    const float* edges = (const float*)d_in[1];
    const unsigned int* mask = (const unsigned int*)d_in[2];
    const float* Wq = (const float*)d_in[3];
    const float* Wk = (const float*)d_in[4];
    const float* Wv = (const float*)d_in[5];
    const float* Wo = (const float*)d_in[6];
    const float* We = (const float*)d_in[7];
    float* out = (float*)d_out;
    float* ws  = (float*)d_ws;
    float* out_e = out + 128 * NN;

    hipLaunchKernelGGL(k_proj, dim3(101), dim3(256), 0, stream,
                       nodes, Wq, Wk, Wv, Wo, We, mask, ws);
    hipLaunchKernelGGL(k_attn, dim3(384, 2), dim3(512), 0, stream,
                       edges, ws);
    hipLaunchKernelGGL(k_comb, dim3(384), dim3(256), 0, stream,
                       ws, ws + WS_GH, out);
    hipLaunchKernelGGL(k_edge, dim3(384, 8), dim3(192), 0, stream,
                       edges, ws, out_e);
}

// Round 13
// 143.366 us; speedup vs baseline: 1.0145x; 1.0145x over previous
//
#include <hip/hip_runtime.h>
#include <math.h>

#define NN 384
#define NSQ (NN*NN)          // 147456

// workspace float offsets
#define WS_MASKF 0           // 384
#define WS_C1    384         // 384*8   = 3072
#define WS_P     3456        // 384*512 = 196608
#define WS_VN    200064      // 384*256 = 98304
#define WS_T     298368      // (unused after fusion; kept for layout stability)
#define WS_GH    494976      // 64*384  = 24576
#define WS_WT    519552      // 64*64 bf16 (2048 floats used)  WtBF[o][c] = We[o,256+c]
#define WS_WOT   523648      // 256*128 = 32768  Wo^T            [dd][o]
#define WS_WVE   556416      // 64*256  = 16384  Wv[:,128:192]^T [c][d]
#define WS_WEN   572800      // 256*64  = 16384  We[:,0:256]^T   [dd][o]

typedef short short8 __attribute__((ext_vector_type(8)));
typedef float f32x4 __attribute__((ext_vector_type(4)));

__device__ __forceinline__ unsigned short f2bf(float x) {
    unsigned u = __float_as_uint(x);
    return (unsigned short)((u + 0x7FFFu + ((u >> 16) & 1u)) >> 16);
}

// ---------------------------------------------------------------------------
// K1: projections + c1 + P. 96 main blocks x 4 columns (R10 occupancy split)
// + FLOAT4 weight-row loads (R11). Aux blocks 96..100: mask / WtBF / WoT /
// WvE / WeN.
__global__ __launch_bounds__(256) void k_proj(
    const float* __restrict__ nodes, const float* __restrict__ Wq,
    const float* __restrict__ Wk, const float* __restrict__ Wv,
    const float* __restrict__ Wo, const float* __restrict__ We,
    const unsigned int* __restrict__ mi, float* __restrict__ ws) {
    int tid = threadIdx.x;
    if (blockIdx.x >= 96) {
        if (blockIdx.x == 96) {
            __shared__ int bytemode;
            if (tid == 0) bytemode = 0;
            __syncthreads();
            unsigned v0 = mi[tid];
            unsigned v1 = (tid < 128) ? mi[256 + tid] : 0u;
            if (v0 > 1u || v1 > 1u) bytemode = 1;   // benign race
            __syncthreads();
            float* maskf = ws + WS_MASKF;
            for (int j = tid; j < NN; j += 256) {
                int on;
                if (bytemode) on = (((const unsigned char*)mi)[j] != 0);
                else          on = (mi[j] != 0u);
                maskf[j] = on ? 1.0f : 0.0f;
            }
        } else if (blockIdx.x == 97) {
            // bf16 weight for k_edge's MFMA: WtBF[o][c] = We[o, 256+c]
            unsigned short* WtBF = reinterpret_cast<unsigned short*>(ws + WS_WT);
            for (int idx = tid; idx < 4096; idx += 256) {
                int o = idx >> 6, c = idx & 63;
                WtBF[o * 64 + c] = f2bf(We[o * 320 + 256 + c]);
            }
        } else if (blockIdx.x == 98) {
            float* WoT = ws + WS_WOT;
            for (int idx = tid; idx < 32768; idx += 256) {
                int dd = idx >> 7, o = idx & 127;
                WoT[dd * 128 + o] = Wo[o * 256 + dd];
            }
        } else if (blockIdx.x == 99) {
            float* WvE = ws + WS_WVE;
            for (int idx = tid; idx < 16384; idx += 256) {
                int c = idx >> 8, d = idx & 255;
                WvE[c * 256 + d] = Wv[d * 192 + 128 + c];
            }
        } else {
            float* WeN = ws + WS_WEN;
            for (int idx = tid; idx < 16384; idx += 256) {
                int dd = idx >> 6, o = idx & 63;
                WeN[dd * 64 + o] = We[o * 320 + dd];
            }
        }
        return;
    }
    float* c1_ws = ws + WS_C1;
    float* P_ws  = ws + WS_P;
    float* vn_ws = ws + WS_VN;
    int i0 = blockIdx.x * 4;
    __shared__ float nl[128][4];
    __shared__ float q_l[256][4];
    __shared__ float qk_l[256][4];
    for (int idx = tid; idx < 512; idx += 256) {
        int m = idx >> 2, ii = idx & 3;
        nl[m][ii] = nodes[m * NN + i0 + ii];
    }
    __syncthreads();
    int o = tid;
    float aq[4], ak[4], av[4];
#pragma unroll
    for (int ii = 0; ii < 4; ii++) { aq[ii] = 0.f; ak[ii] = 0.f; av[ii] = 0.f; }
    {
        const float4* wq4 = reinterpret_cast<const float4*>(Wq + o * 128);
        const float4* wk4 = reinterpret_cast<const float4*>(Wk + o * 192);
        const float4* wv4 = reinterpret_cast<const float4*>(Wv + o * 192);
#pragma unroll 8
        for (int m4 = 0; m4 < 32; m4++) {
            float4 wq = wq4[m4];
            float4 wk = wk4[m4];
            float4 wv = wv4[m4];
#pragma unroll
            for (int s = 0; s < 4; s++) {
                int m = m4 * 4 + s;
                float fq = s == 0 ? wq.x : s == 1 ? wq.y : s == 2 ? wq.z : wq.w;
                float fk = s == 0 ? wk.x : s == 1 ? wk.y : s == 2 ? wk.z : wk.w;
                float fv = s == 0 ? wv.x : s == 1 ? wv.y : s == 2 ? wv.z : wv.w;
#pragma unroll
                for (int ii = 0; ii < 4; ii++) {
                    float nv = nl[m][ii];
                    aq[ii] = fmaf(fq, nv, aq[ii]);
                    ak[ii] = fmaf(fk, nv, ak[ii]);
                    av[ii] = fmaf(fv, nv, av[ii]);
                }
            }
        }
    }
#pragma unroll
    for (int ii = 0; ii < 4; ii++) {
        vn_ws[(size_t)(i0 + ii) * 256 + o] = av[ii];
        q_l[o][ii]  = aq[ii];
        qk_l[o][ii] = aq[ii] * ak[ii];
    }
    __syncthreads();
    if (tid < 32) {
        int h = tid >> 2, ii = tid & 3;
        float s = 0.f;
        for (int a = 0; a < 32; a++) s += qk_l[h * 32 + a][ii];
        c1_ws[(i0 + ii) * 8 + h] = s;
    }
    for (int rep = 0; rep < 2; rep++) {
        int idx = rep * 256 + tid;
        int c = idx & 63, h = idx >> 6;
        float ap[4];
#pragma unroll
        for (int ii = 0; ii < 4; ii++) ap[ii] = 0.f;
        for (int a = 0; a < 32; a++) {
            float w = Wk[(h * 32 + a) * 192 + 128 + c];
#pragma unroll
            for (int ii = 0; ii < 4; ii++)
                ap[ii] = fmaf(q_l[h * 32 + a][ii], w, ap[ii]);
        }
#pragma unroll
        for (int ii = 0; ii < 4; ii++)
            P_ws[(size_t)(i0 + ii) * 512 + c * 8 + h] = ap[ii];
    }
}

// ---------------------------------------------------------------------------
// K2 (FUSED attn + nf): block = row i, 512 threads. (R6 version verbatim —
// best measured; eB handoff (R7), coalesced restage (R8), co-schedule (R9),
// and flash half-row split (R12) all regressed or were neutral.)
__global__ __launch_bounds__(512) void k_attn(
    const float* __restrict__ edges, const float* __restrict__ ws_ro,
    float* __restrict__ gh_ws, float* __restrict__ out) {
    __shared__ __align__(16) unsigned short epad_h[64 * 392];  // 50176 B
    __shared__ __align__(16) float sT2[NN * 8];                // 12288 B
    __shared__ __align__(16) float T_lds[512];                 // 2048 B
    __shared__ float nf_lds[256];                              // 1024 B
    const float* maskf = ws_ro + WS_MASKF;
    const float* c1w   = ws_ro + WS_C1;
    const float* Pw    = ws_ro + WS_P;
    const float* vn_ws = ws_ro + WS_VN;
    const float* WvE   = ws_ro + WS_WVE;
    const float* WoT   = ws_ro + WS_WOT;
    const float* WeN   = ws_ro + WS_WEN;
    int i = blockIdx.x;
    int tid = threadIdx.x;
    int wv = tid >> 6, ln = tid & 63;
    float mask_i = maskf[i];

    if (tid < NN) {
        int j = tid;
        const float* eb = edges + (size_t)i * NN + j;
        const float* Pi = Pw + (size_t)i * 512;
        float acc[8];
#pragma unroll
        for (int h = 0; h < 8; h++) acc[h] = 0.f;
#pragma unroll
        for (int cb = 0; cb < 4; cb++) {
            float ev[16];
#pragma unroll
            for (int t = 0; t < 16; t++)
                ev[t] = eb[(size_t)(cb * 16 + t) * NSQ];
#pragma unroll
            for (int t = 0; t < 16; t++) {
                int c = cb * 16 + t;
                epad_h[c * 392 + j] = f2bf(ev[t]);
                const float* Pc = Pi + c * 8;     // wave-uniform -> s_load
#pragma unroll
                for (int h = 0; h < 8; h++) acc[h] = fmaf(Pc[h], ev[t], acc[h]);
            }
        }
        float mj = maskf[j];
        const float* c1i = c1w + i * 8;
        float sv[8];
#pragma unroll
        for (int h = 0; h < 8; h++) {
            float s = (c1i[h] + acc[h]) * 0.17677669529663687f;
            sv[h] = (mj != 0.0f) ? s : -1e30f;
        }
        *reinterpret_cast<float4*>(&sT2[j * 8])     = make_float4(sv[0], sv[1], sv[2], sv[3]);
        *reinterpret_cast<float4*>(&sT2[j * 8 + 4]) = make_float4(sv[4], sv[5], sv[6], sv[7]);
    }
    __syncthreads();
    // softmax: wave wv owns head h=wv, lanes cover j = ln + 64k
    float v[6];
    {
        int h = wv;
#pragma unroll
        for (int k = 0; k < 6; k++) v[k] = sT2[(ln + 64 * k) * 8 + h];
    }
    __syncthreads();   // all sT2 reads done; safe to overlay s_bf below
    {
        int h = wv;
        float m = v[0];
#pragma unroll
        for (int k = 1; k < 6; k++) m = fmaxf(m, v[k]);
#pragma unroll
        for (int s = 1; s < 64; s <<= 1) m = fmaxf(m, __shfl_xor(m, s));
        float ex[6]; float sum = 0.f;
#pragma unroll
        for (int k = 0; k < 6; k++) { ex[k] = __expf(v[k] - m); sum += ex[k]; }
#pragma unroll
        for (int s = 1; s < 64; s <<= 1) sum += __shfl_xor(sum, s);
        float fac = mask_i / sum;
        unsigned short* s_bf = reinterpret_cast<unsigned short*>(sT2);
#pragma unroll
        for (int k = 0; k < 6; k++)
            s_bf[h * 392 + ln + 64 * k] = f2bf(ex[k] * fac);
    }
    __syncthreads();
    // pass2: 4-wave MFMA. Wave wv (0..3) owns c-tile wv; 12 MFMAs each.
    if (tid < 256) {
        const unsigned short* s_bf = reinterpret_cast<const unsigned short*>(sT2);
        int nc   = ln & 15;
        int quad = ln >> 4;
        int hrow = nc & 7;
        f32x4 acc = {0.f, 0.f, 0.f, 0.f};
#pragma unroll
        for (int s = 0; s < 12; s++) {
            int jb = s * 32 + quad * 8;
            short8 a = *reinterpret_cast<const short8*>(&s_bf[hrow * 392 + jb]);
            short8 b = *reinterpret_cast<const short8*>(&epad_h[(wv * 16 + nc) * 392 + jb]);
            acc = __builtin_amdgcn_mfma_f32_16x16x32_bf16(a, b, acc, 0, 0, 0);
        }
        if (ln < 32) {   // quads 0,1 -> D rows 0..7 (valid h)
#pragma unroll
            for (int r = 0; r < 4; r++) {
                int h = quad * 4 + r;
                T_lds[h * 64 + wv * 16 + nc] = acc[r];
            }
        }
    }
    __syncthreads();
    // tail #1 (was k_nf phase 1): nf[d] = mask_i*vn[i,d] + WvE^T @ T
    if (tid < 256) {
        int d = tid, h = d >> 5;
        float a0 = 0.f, a1 = 0.f, a2 = 0.f, a3 = 0.f;
#pragma unroll
        for (int c = 0; c < 64; c += 4) {
            a0 = fmaf(WvE[(c    ) * 256 + d], T_lds[h * 64 + c    ], a0);
            a1 = fmaf(WvE[(c + 1) * 256 + d], T_lds[h * 64 + c + 1], a1);
            a2 = fmaf(WvE[(c + 2) * 256 + d], T_lds[h * 64 + c + 2], a2);
            a3 = fmaf(WvE[(c + 3) * 256 + d], T_lds[h * 64 + c + 3], a3);
        }
        nf_lds[d] = mask_i * vn_ws[(size_t)i * 256 + d] + ((a0 + a1) + (a2 + a3));
    }
    __syncthreads();
    // tail #2: node_out = Wo@nf ; gh = 0.5 * WeN@nf
    if (tid < 128) {
        int o = tid;
        float b0 = 0.f, b1 = 0.f, b2 = 0.f, b3 = 0.f;
#pragma unroll 8
        for (int dd = 0; dd < 256; dd += 4) {
            b0 = fmaf(WoT[(dd    ) * 128 + o], nf_lds[dd    ], b0);
            b1 = fmaf(WoT[(dd + 1) * 128 + o], nf_lds[dd + 1], b1);
            b2 = fmaf(WoT[(dd + 2) * 128 + o], nf_lds[dd + 2], b2);
            b3 = fmaf(WoT[(dd + 3) * 128 + o], nf_lds[dd + 3], b3);
        }
        out[o * NN + i] = (b0 + b1) + (b2 + b3);
    } else if (tid < 192) {
        int o = tid - 128;
        float b0 = 0.f, b1 = 0.f, b2 = 0.f, b3 = 0.f;
#pragma unroll 8
        for (int dd = 0; dd < 256; dd += 4) {
            b0 = fmaf(WeN[(dd    ) * 64 + o], nf_lds[dd    ], b0);
            b1 = fmaf(WeN[(dd + 1) * 64 + o], nf_lds[dd + 1], b1);
            b2 = fmaf(WeN[(dd + 2) * 64 + o], nf_lds[dd + 2], b2);
            b3 = fmaf(WeN[(dd + 3) * 64 + o], nf_lds[dd + 3], b3);
        }
        gh_ws[o * NN + i] = 0.5f * ((b0 + b1) + (b2 + b3));
    }
}

// ---------------------------------------------------------------------------
// K4: out_e[o,i,j] = gh[o,i]+gh[o,j]+sum_c WtBF[o][c]*e[c,i,j]   via MFMA.
// (R11 version verbatim: jh=8 split, 48 j's/block, 3072 blocks ~10/CU.)
__global__ __launch_bounds__(192) void k_edge(
    const float* __restrict__ edges, const float* __restrict__ ws_ro,
    float* __restrict__ out_e) {
    __shared__ __align__(16) unsigned short eT[48 * 72];  // [j_loc][c], 6912 B
    const unsigned short* WtBF = reinterpret_cast<const unsigned short*>(ws_ro + WS_WT);
    const float* gh = ws_ro + WS_GH;
    int i = blockIdx.x, jh = blockIdx.y, tid = threadIdx.x;

    // phase1: thread (jl = tid%48, ch = tid/48): loads c in [ch*16, ch*16+16)
    // for column j = jh*48 + jl. Lanes -> consecutive j, same c: coalesced.
    {
        int ch = tid / 48, jl = tid - ch * 48;
        int c0 = ch * 16;
        const float* eb = edges + (size_t)c0 * NSQ + (size_t)i * NN + jh * 48 + jl;
        float ev[16];
#pragma unroll
        for (int t = 0; t < 16; t++)
            ev[t] = eb[(size_t)t * NSQ];
        short8 p0, p1;
#pragma unroll
        for (int t = 0; t < 8; t++) p0[t] = (short)f2bf(ev[t]);
#pragma unroll
        for (int t = 0; t < 8; t++) p1[t] = (short)f2bf(ev[t + 8]);
        *reinterpret_cast<short8*>(&eT[jl * 72 + c0])     = p0;
        *reinterpret_cast<short8*>(&eT[jl * 72 + c0 + 8]) = p1;
    }
    __syncthreads();

    // phase2: 3 waves; wave wv owns j-tile wv; all 4 o-tiles.
    int L = tid & 63, wv = tid >> 6;
    int nc = L & 15, quad = L >> 4;
    short8 a00 = *reinterpret_cast<const short8*>(&WtBF[(0 * 16 + nc) * 64 + 0  + quad * 8]);
    short8 a01 = *reinterpret_cast<const short8*>(&WtBF[(0 * 16 + nc) * 64 + 32 + quad * 8]);
    short8 a10 = *reinterpret_cast<const short8*>(&WtBF[(1 * 16 + nc) * 64 + 0  + quad * 8]);
    short8 a11 = *reinterpret_cast<const short8*>(&WtBF[(1 * 16 + nc) * 64 + 32 + quad * 8]);
    short8 a20 = *reinterpret_cast<const short8*>(&WtBF[(2 * 16 + nc) * 64 + 0  + quad * 8]);
    short8 a21 = *reinterpret_cast<const short8*>(&WtBF[(2 * 16 + nc) * 64 + 32 + quad * 8]);
    short8 a30 = *reinterpret_cast<const short8*>(&WtBF[(3 * 16 + nc) * 64 + 0  + quad * 8]);
    short8 a31 = *reinterpret_cast<const short8*>(&WtBF[(3 * 16 + nc) * 64 + 32 + quad * 8]);
    // gh[o, i]: o = ot*16 + quad*4 + r, uniform within 16-lane group.
    float ghi[16];
#pragma unroll
    for (int ot = 0; ot < 4; ot++)
#pragma unroll
        for (int r = 0; r < 4; r++)
            ghi[ot * 4 + r] = gh[(ot * 16 + quad * 4 + r) * NN + i];

    {
        int jt = wv;
        short8 b0 = *reinterpret_cast<const short8*>(&eT[(jt * 16 + nc) * 72 + 0  + quad * 8]);
        short8 b1 = *reinterpret_cast<const short8*>(&eT[(jt * 16 + nc) * 72 + 32 + quad * 8]);
        int j = jh * 48 + jt * 16 + nc;
        f32x4 c0 = {0.f, 0.f, 0.f, 0.f};
        f32x4 c1 = {0.f, 0.f, 0.f, 0.f};
        f32x4 c2 = {0.f, 0.f, 0.f, 0.f};
        f32x4 c3 = {0.f, 0.f, 0.f, 0.f};
        c0 = __builtin_amdgcn_mfma_f32_16x16x32_bf16(a00, b0, c0, 0, 0, 0);
        c0 = __builtin_amdgcn_mfma_f32_16x16x32_bf16(a01, b1, c0, 0, 0, 0);
        c1 = __builtin_amdgcn_mfma_f32_16x16x32_bf16(a10, b0, c1, 0, 0, 0);
        c1 = __builtin_amdgcn_mfma_f32_16x16x32_bf16(a11, b1, c1, 0, 0, 0);
        c2 = __builtin_amdgcn_mfma_f32_16x16x32_bf16(a20, b0, c2, 0, 0, 0);
        c2 = __builtin_amdgcn_mfma_f32_16x16x32_bf16(a21, b1, c2, 0, 0, 0);
        c3 = __builtin_amdgcn_mfma_f32_16x16x32_bf16(a30, b0, c3, 0, 0, 0);
        c3 = __builtin_amdgcn_mfma_f32_16x16x32_bf16(a31, b1, c3, 0, 0, 0);
#pragma unroll
        for (int ot = 0; ot < 4; ot++) {
            f32x4 cc = ot == 0 ? c0 : ot == 1 ? c1 : ot == 2 ? c2 : c3;
#pragma unroll
            for (int r = 0; r < 4; r++) {
                int o = ot * 16 + quad * 4 + r;
                float val = cc[r] + ghi[ot * 4 + r] + gh[o * NN + j];
                __builtin_nontemporal_store(val, &out_e[(size_t)o * NSQ + (size_t)i * NN + j]);
            }
        }
    }
}

// ---------------------------------------------------------------------------
extern "C" void kernel_launch(void* const* d_in, const int* in_sizes, int n_in,
                              void* d_out, int out_size, void* d_ws, size_t ws_size,
                              hipStream_t stream) {
    const float* nodes = (const float*)d_in[0];
    const float* edges = (const float*)d_in[1];
    const unsigned int* mask = (const unsigned int*)d_in[2];
    const float* Wq = (const float*)d_in[3];
    const float* Wk = (const float*)d_in[4];
    const float* Wv = (const float*)d_in[5];
    const float* Wo = (const float*)d_in[6];
    const float* We = (const float*)d_in[7];
    float* out = (float*)d_out;
    float* ws  = (float*)d_ws;
    float* out_e = out + 128 * NN;

    hipLaunchKernelGGL(k_proj, dim3(101), dim3(256), 0, stream,
                       nodes, Wq, Wk, Wv, Wo, We, mask, ws);
    hipLaunchKernelGGL(k_attn, dim3(384), dim3(512), 0, stream,
                       edges, ws, ws + WS_GH, out);
    hipLaunchKernelGGL(k_edge, dim3(384, 8), dim3(192), 0, stream,
                       edges, ws, out_e);
}